// Round 10
// baseline (163.745 us; speedup 1.0000x reference)
//
#include <hip/hip_runtime.h>
#include <math.h>

typedef __bf16 bf16x8 __attribute__((ext_vector_type(8)));
typedef __bf16 bf16x4 __attribute__((ext_vector_type(4)));
typedef float  f32x4  __attribute__((ext_vector_type(4)));

// async global->LDS, 16B per lane; LDS dest = wave-uniform base + lane*16
__device__ __forceinline__ void gload16(const float* g, float* l)
{
    __builtin_amdgcn_global_load_lds(
        (const __attribute__((address_space(1))) void*)g,
        (__attribute__((address_space(3))) void*)l, 16, 0, 0);
}

// ---------------------------------------------------------------------------
// cvt: fp32 -> bf16 for the 4 weight matrices (512x512 each)
// ---------------------------------------------------------------------------
__global__ __launch_bounds__(256)
void cvt_w(const float* __restrict__ w0, const float* __restrict__ w1,
           const float* __restrict__ w2, const float* __restrict__ w3,
           __bf16* __restrict__ d0, __bf16* __restrict__ d1,
           __bf16* __restrict__ d2, __bf16* __restrict__ d3)
{
    const int y = blockIdx.y;
    const float* s = (y == 0) ? w0 : (y == 1) ? w1 : (y == 2) ? w2 : w3;
    __bf16*      d = (y == 0) ? d0 : (y == 1) ? d1 : (y == 2) ? d2 : d3;
    const int i = blockIdx.x * 256 + threadIdx.x;
    float4 a = *(const float4*)(s + (size_t)i * 8);
    float4 b = *(const float4*)(s + (size_t)i * 8 + 4);
    bf16x8 v;
    v[0] = (__bf16)a.x; v[1] = (__bf16)a.y; v[2] = (__bf16)a.z; v[3] = (__bf16)a.w;
    v[4] = (__bf16)b.x; v[5] = (__bf16)b.y; v[6] = (__bf16)b.z; v[7] = (__bf16)b.w;
    *(bf16x8*)(d + (size_t)i * 8) = v;
}

// ---------------------------------------------------------------------------
// Fused QKV projection, z-merged (R8-proven). Tile 64x64, grid (64,8) = 512
// blocks = 2/CU (was 1/CU: 1 wave/SIMD left load latency exposed).
// ---------------------------------------------------------------------------
__global__ __launch_bounds__(256, 2)
void qkv_proj(const float* __restrict__ X,
              const __bf16* __restrict__ Wqb, const __bf16* __restrict__ Wkb,
              const __bf16* __restrict__ Wvb,
              const float* __restrict__ bq, const float* __restrict__ bk,
              const float* __restrict__ bv,
              __bf16* __restrict__ qTb, __bf16* __restrict__ kTb,
              __bf16* __restrict__ vTb)
{
    const int tid  = threadIdx.x;
    const int w    = tid >> 6;
    const int lane = tid & 63;
    const int lq   = lane & 15;
    const int quad = lane >> 4;
    const int n0    = blockIdx.x * 64 + (w >> 1) * 32;
    const int obase = blockIdx.y * 64 + (w & 1) * 32;

    const __bf16* const Wz[3] = { Wqb, Wkb, Wvb };

    f32x4 acc[3][2][2] = {};
    for (int k0 = 0; k0 < 512; k0 += 32) {
        bf16x8 af[2];
#pragma unroll
        for (int m = 0; m < 2; m++) {
            const float* xp = X + (size_t)(n0 + m * 16 + lq) * 512 + k0 + quad * 8;
            float4 x0 = *(const float4*)xp;
            float4 x1 = *(const float4*)(xp + 4);
            bf16x8 v;
            v[0] = (__bf16)x0.x; v[1] = (__bf16)x0.y; v[2] = (__bf16)x0.z; v[3] = (__bf16)x0.w;
            v[4] = (__bf16)x1.x; v[5] = (__bf16)x1.y; v[6] = (__bf16)x1.z; v[7] = (__bf16)x1.w;
            af[m] = v;
        }
#pragma unroll
        for (int z = 0; z < 3; z++) {
            bf16x8 bfr[2];
#pragma unroll
            for (int nn = 0; nn < 2; nn++)
                bfr[nn] = *(const bf16x8*)(Wz[z] + (size_t)(obase + nn * 16 + lq) * 512 + k0 + quad * 8);
#pragma unroll
            for (int m = 0; m < 2; m++)
#pragma unroll
                for (int nn = 0; nn < 2; nn++)
                    acc[z][m][nn] = __builtin_amdgcn_mfma_f32_16x16x32_bf16(af[m], bfr[nn], acc[z][m][nn], 0, 0, 0);
        }
    }

    const float* const ba[3] = { bq, bk, bv };
    const float scaling = 0.17677669529663687f;
#pragma unroll
    for (int z = 0; z < 3; z++)
#pragma unroll
        for (int m = 0; m < 2; m++)
#pragma unroll
            for (int nn = 0; nn < 2; nn++)
#pragma unroll
                for (int r = 0; r < 4; r++) {
                    const int n = n0 + m * 16 + quad * 4 + r;
                    const int o = obase + nn * 16 + lq;
                    float val = acc[z][m][nn][r] + ba[z][o];
                    const int t = n >> 2, b = n & 3;
                    const int h = o >> 5, d = o & 31;
                    const int bh = b * 16 + h;
                    if (z == 0)
                        qTb[(((size_t)bh * 1024 + t) << 5) + d] = (__bf16)(val * scaling);
                    else if (z == 1)
                        kTb[(((size_t)bh * 1024 + t) << 5) + d] = (__bf16)val;
                    else
                        vTb[(((size_t)bh * 32 + d) << 10) + t] = (__bf16)val;
                }
}

// ---------------------------------------------------------------------------
// Out projection. Tile 64x64, grid (64,8) = 512 blocks = 2/CU.
// ---------------------------------------------------------------------------
__global__ __launch_bounds__(256, 2)
void out_proj(const __bf16* __restrict__ A, const __bf16* __restrict__ Wb,
              const float* __restrict__ bias, float* __restrict__ out)
{
    const int tid  = threadIdx.x;
    const int w    = tid >> 6;
    const int lane = tid & 63;
    const int lq   = lane & 15;
    const int quad = lane >> 4;
    const int n0    = blockIdx.x * 64 + (w >> 1) * 32;
    const int obase = blockIdx.y * 64 + (w & 1) * 32;

    f32x4 acc[2][2] = {};
    for (int k0 = 0; k0 < 512; k0 += 32) {
        bf16x8 af[2], bfr[2];
#pragma unroll
        for (int m = 0; m < 2; m++)
            af[m] = *(const bf16x8*)(A + (size_t)(n0 + m * 16 + lq) * 512 + k0 + quad * 8);
#pragma unroll
        for (int nn = 0; nn < 2; nn++)
            bfr[nn] = *(const bf16x8*)(Wb + (size_t)(obase + nn * 16 + lq) * 512 + k0 + quad * 8);
#pragma unroll
        for (int m = 0; m < 2; m++)
#pragma unroll
            for (int nn = 0; nn < 2; nn++)
                acc[m][nn] = __builtin_amdgcn_mfma_f32_16x16x32_bf16(af[m], bfr[nn], acc[m][nn], 0, 0, 0);
    }
#pragma unroll
    for (int m = 0; m < 2; m++)
#pragma unroll
        for (int nn = 0; nn < 2; nn++)
#pragma unroll
            for (int r = 0; r < 4; r++) {
                const int n = n0 + m * 16 + quad * 4 + r;
                const int o = obase + nn * 16 + lq;
                out[(size_t)n * 512 + o] = acc[m][nn][r] + bias[o];
            }
}

// ---------------------------------------------------------------------------
// MFMA attention with LDS-STAGED bias (the point of this round).
//
// The bias was the one stream with scattered DRAM access (64-B segments at
// 4-KB stride via per-lane f32x4 C-operand loads) -> measured ~38% HBM
// efficiency, which set the whole attn period. Here each head's 64-KB bias
// tile is staged into LDS with global_load_lds at 1 KB CONTIGUOUS per
// instruction (wave w stages rows 2w,2w+1 = 8 KB contiguous), double
// buffered; QK reads C-fragments from LDS. Conflict-free via a 16-B-granule
// XOR swizzle (granule g stored at g ^ ((row&7)<<1)) applied on the per-lane
// GLOBAL source (LDS dest stays linear) and identically on the read.
//
// LDS = 2x64KB bias + 32KB X-region = exactly 160 KiB -> 1 block/CU ->
// 256-VGPR budget. X-region per-wave 4 KB slice: P (bf16, XOR-swizzled,
// whole slice) -> dead before Op [0,528)f / red [544,560)f are written.
// Waits: staging issued pre-QK (youngest VMEM, ~90% in-flight window);
// B1 = lgkm-only; B2 = vmcnt(1)+lgkm(0) (drains staging+qa, leaves the
// attnb store in flight) + barrier. Never vmcnt(0) mid-stream.
// ---------------------------------------------------------------------------
__global__ __attribute__((amdgpu_waves_per_eu(2, 2))) __launch_bounds__(512)
void attn_mfma(const __bf16* __restrict__ qTb, const __bf16* __restrict__ kTb,
               const __bf16* __restrict__ vTb, const float* __restrict__ bias,
               const int* __restrict__ mask, __bf16* __restrict__ attnb,
               float* __restrict__ avgf)
{
    // [0,16384)f buf0, [16384,32768)f buf1, [32768,40960)f X (8 x 1024f)
    __shared__ float smem[40960];

    const int tid  = threadIdx.x;
    const int w    = tid >> 6;
    const int lane = tid & 63;
    const int lq   = lane & 15;
    const int quad = lane >> 4;

    // bijective XCD swizzle: 256 blocks -> 32-block contiguous chunk per XCD
    const int bid = blockIdx.y * 64 + blockIdx.x;
    const int nb  = (bid & 7) * 32 + (bid >> 3);
    const int t0  = (nb & 63) * 16;
    const int b   = nb >> 6;
    const int sbase = w * 128;

    // pack 32 mask bits (s = sbase + j*16 + quad*4 + r)
    unsigned mbits = 0;
    {
        const int* mp = mask + b * 1024 + sbase + quad * 4;
#pragma unroll
        for (int j = 0; j < 8; j++) {
            int4 m4 = *(const int4*)(mp + j * 16);
            mbits |= (unsigned)(m4.x != 0) << (j * 4 + 0);
            mbits |= (unsigned)(m4.y != 0) << (j * 4 + 1);
            mbits |= (unsigned)(m4.z != 0) << (j * 4 + 2);
            mbits |= (unsigned)(m4.w != 0) << (j * 4 + 3);
        }
    }

    const __bf16* const qp0 = qTb + (((size_t)(b * 16) * 1024 + t0) << 5) +
                              lq * 32 + quad * 8;
    const __bf16* const kp0 = kTb + ((size_t)(b * 16) << 15);
    const __bf16* const vp0 = vTb + ((size_t)(b * 16) << 15);
    const float*  const bias0 = bias + (((size_t)(b * 16)) << 20) + (size_t)t0 * 1024;

    // prologue: stage head 0 into buf0 (contiguous source, swizzled), qa(0)
    bf16x8 qa = *(const bf16x8*)qp0;
#pragma unroll
    for (int c = 0; c < 8; c++) {
        const int row = 2 * w + (c >> 2), qtr = c & 3;
        const int g   = (qtr * 64 + lane) ^ ((row & 7) << 1);
        gload16(bias0 + (size_t)row * 1024 + g * 4, &smem[row * 1024 + qtr * 256]);
    }
    __syncthreads();

    float avg_reg[32] = {};
    float* const Xw = &smem[32768 + w * 1024];
    __bf16* const Pw = (__bf16*)Xw;
    const int psw = (lq & 7) << 3;       // P XOR swizzle (bf16 units)
    const int csw = (lq & 7) << 1;       // bias granule XOR for this lane-row

    for (int hh = 0; hh < 16; hh++) {
        const int cur = hh & 1;
        const __bf16* kp = kp0 + ((size_t)hh << 15);
        const __bf16* vp = vp0 + ((size_t)hh << 15);

        // --- K + V loads first (oldest VMEM of the head) ---
        bf16x8 kb[8];
#pragma unroll
        for (int j = 0; j < 8; j++)
            kb[j] = *(const bf16x8*)(kp + (size_t)(sbase + j * 16 + lq) * 32 + quad * 8);
        bf16x8 v0r[4], v1r[4];
#pragma unroll
        for (int ks = 0; ks < 4; ks++) {
            v0r[ks] = *(const bf16x8*)(vp + (size_t)lq * 1024 + sbase + ks * 32 + quad * 8);
            v1r[ks] = *(const bf16x8*)(vp + (size_t)(16 + lq) * 1024 + sbase + ks * 32 + quad * 8);
        }
        __builtin_amdgcn_sched_barrier(0);

        // --- stage bias(h+1) + qa(h+1): youngest VMEM, in flight until B2 ---
        bf16x8 qan = qa;
        if (hh < 15) {
            const float* bsrc = bias0 + ((size_t)(hh + 1) << 20);
            float* ldst = &smem[(cur ^ 1) * 16384];
#pragma unroll
            for (int c = 0; c < 8; c++) {
                const int row = 2 * w + (c >> 2), qtr = c & 3;
                const int g   = (qtr * 64 + lane) ^ ((row & 7) << 1);
                gload16(bsrc + (size_t)row * 1024 + g * 4, ldst + row * 1024 + qtr * 256);
            }
            qan = *(const bf16x8*)(qp0 + ((size_t)(hh + 1) << 15));
        }
        __builtin_amdgcn_sched_barrier(0);

        // --- QK: C from the staged LDS tile (swizzled read, bank-uniform) ---
        f32x4 acc[8];
        const float* cbase = &smem[cur * 16384 + lq * 1024];
#pragma unroll
        for (int j = 0; j < 8; j++) {
            const int g = w * 32 + j * 4 + quad;
            f32x4 cjv = *(const f32x4*)(cbase + ((g ^ csw) << 2));
            acc[j] = __builtin_amdgcn_mfma_f32_16x16x32_bf16(kb[j], qa, cjv, 0, 0, 0);
        }
        qa = qan;
        __builtin_amdgcn_sched_barrier(0);

        // exp (no max pass; scores bounded) + mask + row partial sum
        float sm = 0.f;
#pragma unroll
        for (int j = 0; j < 8; j++)
#pragma unroll
            for (int r = 0; r < 4; r++) {
                float p = __expf(acc[j][r]);
                p = ((mbits >> (j * 4 + r)) & 1u) ? 0.f : p;
                acc[j][r] = p;
                sm += p;
            }
        sm += __shfl_xor(sm, 16);
        sm += __shfl_xor(sm, 32);

        // unnormalized bf16 P into this wave's X slice (XOR-swizzled)
#pragma unroll
        for (int j = 0; j < 8; j++) {
            bf16x4 pv;
            pv[0] = (__bf16)acc[j][0]; pv[1] = (__bf16)acc[j][1];
            pv[2] = (__bf16)acc[j][2]; pv[3] = (__bf16)acc[j][3];
            *(bf16x4*)&Pw[lq * 128 + ((j * 16 + quad * 4) ^ psw)] = pv;
        }

        // PV: P from LDS, V in regs (V older than staging -> no stage drain)
        f32x4 o0 = {0.f, 0.f, 0.f, 0.f}, o1 = {0.f, 0.f, 0.f, 0.f};
#pragma unroll
        for (int ks = 0; ks < 4; ks++) {
            bf16x8 pa = *(const bf16x8*)&Pw[lq * 128 + ((ks * 32 + quad * 8) ^ psw)];
            o0 = __builtin_amdgcn_mfma_f32_16x16x32_bf16(pa, v0r[ks], o0, 0, 0, 0);
            o1 = __builtin_amdgcn_mfma_f32_16x16x32_bf16(pa, v1r[ks], o1, 0, 0, 0);
        }

        // Op / red overlay the X slice (P is dead after the PV reads)
#pragma unroll
        for (int r = 0; r < 4; r++) {
            Xw[(quad * 4 + r) * 33 + lq]      = o0[r];
            Xw[(quad * 4 + r) * 33 + 16 + lq] = o1[r];
        }
        if (lane < 16) Xw[544 + lane] = sm;

        // B1: lgkm-only drain; bias staging (VMEM) stays in flight.
        __builtin_amdgcn_sched_barrier(0);
        asm volatile("s_waitcnt lgkmcnt(0)" ::: "memory");
        __builtin_amdgcn_s_barrier();
        __builtin_amdgcn_sched_barrier(0);

        // cross-wave reduce: normalized O write
        {
            const int t = tid >> 5, d = tid & 31;
            float s = 0.f, o = 0.f;
#pragma unroll
            for (int w2 = 0; w2 < 8; w2++) s += smem[32768 + w2 * 1024 + 544 + t];
#pragma unroll
            for (int w2 = 0; w2 < 8; w2++) o += smem[32768 + w2 * 1024 + t * 33 + d];
            attnb[((size_t)(t0 + t) * 4 + b) * 512 + hh * 32 + d] = (__bf16)(o / s);
        }

        // inv for this lane's rows (t = lq) + avg fold; acc dies here
        float s_all = 0.f;
#pragma unroll
        for (int w2 = 0; w2 < 8; w2++) s_all += smem[32768 + w2 * 1024 + 544 + lq];
        const float inv = 1.0f / s_all;
#pragma unroll
        for (int j = 0; j < 8; j++)
#pragma unroll
            for (int r = 0; r < 4; r++)
                avg_reg[j * 4 + r] += acc[j][r] * inv;

        // B2: vmcnt(1) -> staging+qa complete (attnb store stays in flight);
        // barrier -> next head may read the staged buffer and overwrite X.
        __builtin_amdgcn_sched_barrier(0);
        asm volatile("s_waitcnt vmcnt(1) lgkmcnt(0)" ::: "memory");
        __builtin_amdgcn_sched_barrier(0);
        __builtin_amdgcn_s_barrier();
        __builtin_amdgcn_sched_barrier(0);
    }

    // head-mean store: single fp32 write (all 16 heads accumulated here)
    float* ap = avgf + ((size_t)(b * 1024 + t0 + lq) << 10) + sbase + quad * 4;
#pragma unroll
    for (int j = 0; j < 8; j++) {
        f32x4 v = { avg_reg[j * 4 + 0] * 0.0625f, avg_reg[j * 4 + 1] * 0.0625f,
                    avg_reg[j * 4 + 2] * 0.0625f, avg_reg[j * 4 + 3] * 0.0625f };
        *(f32x4*)(ap + j * 16) = v;
    }
}

// ---------------------------------------------------------------------------
extern "C" void kernel_launch(void* const* d_in, const int* in_sizes, int n_in,
                              void* d_out, int out_size, void* d_ws, size_t ws_size,
                              hipStream_t stream)
{
    const float* query     = (const float*)d_in[0];
    const float* attn_bias = (const float*)d_in[1];
    const int*   mask      = (const int*)d_in[2];
    const float* q_w       = (const float*)d_in[3];
    const float* q_b       = (const float*)d_in[4];
    const float* k_w       = (const float*)d_in[5];
    const float* k_b       = (const float*)d_in[6];
    const float* v_w       = (const float*)d_in[7];
    const float* v_b       = (const float*)d_in[8];
    const float* out_w     = (const float*)d_in[9];
    const float* out_b     = (const float*)d_in[10];

    float* out     = (float*)d_out;                 // [1024,4,512]
    float* avg_out = out + (size_t)2097152;         // [4,1024,1024]

    char* wsb = (char*)d_ws;
    __bf16* Wqb   = (__bf16*)(wsb);                         // 512 KB
    __bf16* Wkb   = (__bf16*)(wsb + ((size_t)512 << 10));
    __bf16* Wvb   = (__bf16*)(wsb + ((size_t)1 << 20));
    __bf16* Wob   = (__bf16*)(wsb + ((size_t)1 << 20) + ((size_t)512 << 10));
    __bf16* qTb   = (__bf16*)(wsb + ((size_t)2  << 20));    // 4 MB [64][1024][32]
    __bf16* kTb   = (__bf16*)(wsb + ((size_t)6  << 20));    // 4 MB [64][1024][32]
    __bf16* vTb   = (__bf16*)(wsb + ((size_t)10 << 20));    // 4 MB [64][32][1024]
    __bf16* attnb = (__bf16*)(wsb + ((size_t)14 << 20));    // 4 MB [4096][512]

    cvt_w<<<dim3(128, 4), dim3(256), 0, stream>>>(
        q_w, k_w, v_w, out_w, Wqb, Wkb, Wvb, Wob);

    qkv_proj<<<dim3(64, 8), dim3(256), 0, stream>>>(
        query, Wqb, Wkb, Wvb, q_b, k_b, v_b, qTb, kTb, vTb);

    attn_mfma<<<dim3(64, 4), dim3(512), 0, stream>>>(
        qTb, kTb, vTb, attn_bias, mask, attnb, avg_out);

    out_proj<<<dim3(64, 8), dim3(256), 0, stream>>>(attnb, Wob, out_b, out);
}